// Round 2
// baseline (202.085 us; speedup 1.0000x reference)
//
#include <hip/hip_runtime.h>

// x: [4096, 8192] fp32. depth: [3] fp32.
// out: [4096, 3, 1024] uint8 values, stored by the harness as int32 (integer output path).
// One thread per (row, byte) pair: reads 8 floats, emits 3 packed bytes (one per threshold).

constexpr int ROWS = 4096;
constexpr int COLS = 8192;               // floats per row
constexpr int BYTES_PER_ROW = COLS / 8;  // 1024 packed bytes per row per depth

__global__ __launch_bounds__(256) void binarize_pack_kernel(
    const float* __restrict__ x,
    const float* __restrict__ depth,
    int* __restrict__ out) {
    const int tid = blockIdx.x * blockDim.x + threadIdx.x;  // 0 .. ROWS*BYTES_PER_ROW-1

    const float d0 = depth[0];
    const float d1 = depth[1];
    const float d2 = depth[2];

    // 8 consecutive input floats, coalesced: lane i reads bytes [32*i, 32*i+32)
    const float4* xv = reinterpret_cast<const float4*>(x) + (size_t)tid * 2;
    const float4 a = xv[0];
    const float4 b = xv[1];

    const float v[8] = {a.x, a.y, a.z, a.w, b.x, b.y, b.z, b.w};

    unsigned p0 = 0, p1 = 0, p2 = 0;
#pragma unroll
    for (int k = 0; k < 8; ++k) {
        const unsigned w = 1u << (7 - k);  // big-endian bit order
        p0 |= (v[k] > d0) ? w : 0u;
        p1 |= (v[k] > d1) ? w : 0u;
        p2 |= (v[k] > d2) ? w : 0u;
    }

    const int row = tid >> 10;   // / BYTES_PER_ROW
    const int col = tid & 1023;  // % BYTES_PER_ROW
    int* o = out + (size_t)row * (3 * BYTES_PER_ROW) + col;
    o[0 * BYTES_PER_ROW] = (int)p0;
    o[1 * BYTES_PER_ROW] = (int)p1;
    o[2 * BYTES_PER_ROW] = (int)p2;
}

extern "C" void kernel_launch(void* const* d_in, const int* in_sizes, int n_in,
                              void* d_out, int out_size, void* d_ws, size_t ws_size,
                              hipStream_t stream) {
    const float* x = (const float*)d_in[0];
    const float* depth = (const float*)d_in[1];
    int* out = (int*)d_out;

    const int total_threads = ROWS * BYTES_PER_ROW;  // 4,194,304
    const int block = 256;
    const int grid = total_threads / block;          // 16384
    binarize_pack_kernel<<<grid, block, 0, stream>>>(x, depth, out);
}

// Round 4
// 197.235 us; speedup vs baseline: 1.0246x; 1.0246x over previous
//
#include <hip/hip_runtime.h>

// x: [4096, 8192] fp32. depth: [3] fp32.
// out: [4096, 3, 1024] uint8 values, stored by the harness as int32 (integer output path).
// Grid-stride: each thread handles ITERS byte-positions; per iteration it reads
// 8 consecutive floats (2 x float4, 32 B/lane fully coalesced) and writes 3 int32s
// (one per threshold plane). Non-temporal: streaming data, zero reuse.

typedef float nfloat4 __attribute__((ext_vector_type(4)));  // native vec for nontemporal builtins

constexpr int ROWS = 4096;
constexpr int COLS = 8192;               // floats per row
constexpr int BYTES_PER_ROW = COLS / 8;  // 1024 packed bytes per row per depth
constexpr int TOTAL = ROWS * BYTES_PER_ROW;  // 4,194,304 output byte-positions per plane
constexpr int BLOCK = 256;
constexpr int ITERS = 8;
constexpr int GRID = TOTAL / (BLOCK * ITERS);  // 2048 blocks

__global__ __launch_bounds__(BLOCK) void binarize_pack_kernel(
    const float* __restrict__ x,
    const float* __restrict__ depth,
    int* __restrict__ out) {
    const int tid0 = blockIdx.x * BLOCK + threadIdx.x;
    const int stride = GRID * BLOCK;  // 524,288

    const float d0 = depth[0];
    const float d1 = depth[1];
    const float d2 = depth[2];

#pragma unroll
    for (int it = 0; it < ITERS; ++it) {
        const int tid = tid0 + it * stride;

        const nfloat4* xv = reinterpret_cast<const nfloat4*>(x) + (size_t)tid * 2;
        const nfloat4 a = __builtin_nontemporal_load(xv);
        const nfloat4 b = __builtin_nontemporal_load(xv + 1);

        const float v[8] = {a.x, a.y, a.z, a.w, b.x, b.y, b.z, b.w};

        unsigned p0 = 0, p1 = 0, p2 = 0;
#pragma unroll
        for (int k = 0; k < 8; ++k) {
            const unsigned w = 1u << (7 - k);  // big-endian bit order
            p0 |= (v[k] > d0) ? w : 0u;
            p1 |= (v[k] > d1) ? w : 0u;
            p2 |= (v[k] > d2) ? w : 0u;
        }

        const int row = tid >> 10;   // / BYTES_PER_ROW
        const int col = tid & 1023;  // % BYTES_PER_ROW
        int* o = out + (size_t)row * (3 * BYTES_PER_ROW) + col;
        __builtin_nontemporal_store((int)p0, o + 0 * BYTES_PER_ROW);
        __builtin_nontemporal_store((int)p1, o + 1 * BYTES_PER_ROW);
        __builtin_nontemporal_store((int)p2, o + 2 * BYTES_PER_ROW);
    }
}

extern "C" void kernel_launch(void* const* d_in, const int* in_sizes, int n_in,
                              void* d_out, int out_size, void* d_ws, size_t ws_size,
                              hipStream_t stream) {
    const float* x = (const float*)d_in[0];
    const float* depth = (const float*)d_in[1];
    int* out = (int*)d_out;

    binarize_pack_kernel<<<GRID, BLOCK, 0, stream>>>(x, depth, out);
}